// Round 5
// baseline (242.093 us; speedup 1.0000x reference)
//
#include <hip/hip_runtime.h>

// out[b,e,t] = v2[t]*x[b,e,t] + sum_{s<t} v[s]*x[b,e,s]*d^(t-s) + bias[t]
// => decayed prefix scan along the last axis (first-order linear recurrence).
//
// Round-4 structure: 512 threads/block, 4 contiguous elems/thread (perfectly
// coalesced float4 on load+store), 8 ROWS per block with 1-row prefetch so
// HBM latency hides under the previous row's scan. weight/diag/bias are
// loaded ONCE per block. Scan chain halved vs round-3: in the (s,p)
// pair-scan every updating lane's p is the uniform scalar d^(4*2^k), so only
// s needs shuffling (6 shfl + 1 exclusive shift). Cross-wave combine via
// double-buffered LDS (one __syncthreads per row) with scalar d^256;
// per-thread carry uses precomputed d^(4*lane).

#define SEQ 2048
#define THREADS 512
#define ROWS_PER_BLOCK 8

__global__ __launch_bounds__(THREADS, 8) void decay_scan_kernel(
    const float* __restrict__ x,
    const float* __restrict__ weight,
    const float* __restrict__ diag_weight,
    const float* __restrict__ bias,
    const float* __restrict__ decay,
    float* __restrict__ out)
{
    const int tid  = threadIdx.x;
    const int lane = tid & 63;
    const int wv   = tid >> 6;          // 8 waves
    const int off  = tid * 4;           // 16 B stride => fully coalesced
    const long base = (long)blockIdx.x * ROWS_PER_BLOCK * SEQ;

    // d = clip(decay_value[1,0], 0.9, 1.0)
    const float d = fminf(fmaxf(decay[1], 0.9f), 1.0f);
    const float d2 = d * d, d3 = d2 * d;

    // dq[k] = d^(4*2^k), k=0..6  (d^4 ... d^256), by repeated squaring.
    float dq[7];
    dq[0] = d2 * d2;
    #pragma unroll
    for (int k = 1; k < 7; ++k) dq[k] = dq[k - 1] * dq[k - 1];
    const float d256 = dq[6];
    // dpow = d^(4*lane)
    float dpow = 1.f;
    #pragma unroll
    for (int k = 0; k < 6; ++k) if ((lane >> k) & 1) dpow *= dq[k];

    // Broadcast arrays: load once per block.
    const float4 vv = *(const float4*)(weight + off);
    const float4 gv = *(const float4*)(diag_weight + off);
    const float4 bv = *(const float4*)(bias + off);

    __shared__ float ws[2][8];          // double-buffered wave totals

    float4 xv = *(const float4*)(x + base + off);   // prefetch row 0

    #pragma unroll
    for (int r = 0; r < ROWS_PER_BLOCK; ++r) {
        float4 xn;
        if (r + 1 < ROWS_PER_BLOCK)
            xn = *(const float4*)(x + base + (long)(r + 1) * SEQ + off);

        const float xa[4] = {xv.x, xv.y, xv.z, xv.w};

        // Local decayed scan over 4 elems; c ends as the chunk aggregate.
        float lp1, lp2, lp3;
        float c;
        c = d * (xa[0] * vv.x);            lp1 = c;
        c = d * fmaf(xa[1], vv.y, c);      lp2 = c;
        c = d * fmaf(xa[2], vv.z, c);      lp3 = c;
        c = d * fmaf(xa[3], vv.w, c);

        // Wave inclusive scan on s; decay factors are uniform scalars dq[k].
        float s = c;
        #pragma unroll
        for (int k = 0; k < 6; ++k) {
            const int o = 1 << k;
            const float s2 = __shfl_up(s, o, 64);
            if (lane >= o) s = fmaf(s2, dq[k], s);
        }
        // Exclusive (within-wave) carry for this thread's chunk start.
        float es = __shfl_up(s, 1, 64);
        if (lane == 0) es = 0.f;

        // Cross-wave combine through double-buffered LDS; 1 barrier/row.
        if (lane == 63) ws[r & 1][wv] = s;
        __syncthreads();
        float cs = 0.f;
        const float* wrow = ws[r & 1];
        #pragma unroll
        for (int w = 0; w < 7; ++w) {
            if (w < wv) cs = fmaf(cs, d256, wrow[w]);
        }
        // Full exclusive prefix at this thread's chunk start.
        const float C = fmaf(cs, dpow, es);

        // Epilogue: out[k] = C*d^k + lp[k] + x[k]*v2[k] + b[k].
        float4 o4;
        o4.x = fmaf(xa[0], gv.x, C                + bv.x);
        o4.y = fmaf(xa[1], gv.y, fmaf(C, d,  lp1) + bv.y);
        o4.z = fmaf(xa[2], gv.z, fmaf(C, d2, lp2) + bv.z);
        o4.w = fmaf(xa[3], gv.w, fmaf(C, d3, lp3) + bv.w);
        *(float4*)(out + base + (long)r * SEQ + off) = o4;

        xv = xn;
    }
}

extern "C" void kernel_launch(void* const* d_in, const int* in_sizes, int n_in,
                              void* d_out, int out_size, void* d_ws, size_t ws_size,
                              hipStream_t stream) {
    const float* x           = (const float*)d_in[0];
    const float* weight      = (const float*)d_in[1];
    const float* diag_weight = (const float*)d_in[2];
    const float* bias        = (const float*)d_in[3];
    const float* decay       = (const float*)d_in[4];
    float* out = (float*)d_out;

    const int rows = in_sizes[0] / SEQ;  // B*E = 16384
    decay_scan_kernel<<<rows / ROWS_PER_BLOCK, THREADS, 0, stream>>>(
        x, weight, diag_weight, bias, decay, out);
}

// Round 7
// 239.449 us; speedup vs baseline: 1.0110x; 1.0110x over previous
//
#include <hip/hip_runtime.h>

// out[b,e,t] = v2[t]*x[b,e,t] + sum_{s<t} v[s]*x[b,e,s]*d^(t-s) + bias[t]
// => decayed prefix scan along the last axis.
//
// Round-5: exploit ROW INDEPENDENCE for ILP. Each thread carries 4 rows at
// once: 4 interleaved shfl-scan chains (ds_bpermute latency overlaps 4-way),
// one __syncthreads per 4-row group (vs per row), and 4-float4 load/store
// bursts. 8 rows/block in 2 groups; group g+1's loads prefetch under group
// g's scan. Scan algebra identical to round-4 (uniform decay powers dq[k],
// per-lane d^(4*lane), cross-wave d^256).

#define SEQ 2048
#define THREADS 512
#define G 4
#define NGROUPS 2
#define ROWS_PER_BLOCK (G * NGROUPS)

__global__ __launch_bounds__(THREADS) void decay_scan_kernel(
    const float* __restrict__ x,
    const float* __restrict__ weight,
    const float* __restrict__ diag_weight,
    const float* __restrict__ bias,
    const float* __restrict__ decay,
    float* __restrict__ out)
{
    const int tid  = threadIdx.x;
    const int lane = tid & 63;
    const int wv   = tid >> 6;          // 8 waves
    const int off  = tid * 4;           // 16 B stride => fully coalesced
    const long base = (long)blockIdx.x * ROWS_PER_BLOCK * SEQ;

    // d = clip(decay_value[1,0], 0.9, 1.0)
    const float d = fminf(fmaxf(decay[1], 0.9f), 1.0f);
    const float d2 = d * d, d3 = d2 * d;

    // dq[k] = d^(4*2^k), k=0..5 (d^4..d^128); d256 for cross-wave combine.
    float dq[6];
    dq[0] = d2 * d2;
    #pragma unroll
    for (int k = 1; k < 6; ++k) dq[k] = dq[k - 1] * dq[k - 1];
    const float d256 = dq[5] * dq[5];
    // dpow = d^(4*lane)
    float dpow = 1.f;
    #pragma unroll
    for (int k = 0; k < 6; ++k) if ((lane >> k) & 1) dpow *= dq[k];

    // Broadcast arrays: load once per block.
    const float4 vv = *(const float4*)(weight + off);
    const float4 gv = *(const float4*)(diag_weight + off);
    const float4 bv = *(const float4*)(bias + off);

    __shared__ float ws[NGROUPS][G][8];   // wave totals, buffered per group

    // Load burst: group 0's 4 rows (4 independent coalesced float4).
    float4 xv[G];
    #pragma unroll
    for (int r = 0; r < G; ++r)
        xv[r] = *(const float4*)(x + base + (long)r * SEQ + off);

    #pragma unroll
    for (int grp = 0; grp < NGROUPS; ++grp) {
        // Prefetch next group's rows under this group's scan.
        float4 xn[G];
        if (grp + 1 < NGROUPS) {
            #pragma unroll
            for (int r = 0; r < G; ++r)
                xn[r] = *(const float4*)(x + base + (long)((grp + 1) * G + r) * SEQ + off);
        }

        // Local decayed scans — 4 independent chains.
        float lp1[G], lp2[G], lp3[G], s[G];
        #pragma unroll
        for (int r = 0; r < G; ++r) {
            float c;
            c = d * (xv[r].x * vv.x);        lp1[r] = c;
            c = d * fmaf(xv[r].y, vv.y, c);  lp2[r] = c;
            c = d * fmaf(xv[r].z, vv.z, c);  lp3[r] = c;
            c = d * fmaf(xv[r].w, vv.w, c);
            s[r] = c;
        }

        // Wave scans, 4 chains interleaved: shfl latencies overlap 4-way.
        #pragma unroll
        for (int k = 0; k < 6; ++k) {
            const int o = 1 << k;
            float t[G];
            #pragma unroll
            for (int r = 0; r < G; ++r) t[r] = __shfl_up(s[r], o, 64);
            #pragma unroll
            for (int r = 0; r < G; ++r) if (lane >= o) s[r] = fmaf(t[r], dq[k], s[r]);
        }
        float es[G];
        #pragma unroll
        for (int r = 0; r < G; ++r) {
            es[r] = __shfl_up(s[r], 1, 64);
            if (lane == 0) es[r] = 0.f;
        }

        // Cross-wave combine: ONE barrier per 4 rows.
        if (lane == 63) {
            #pragma unroll
            for (int r = 0; r < G; ++r) ws[grp][r][wv] = s[r];
        }
        __syncthreads();

        // Epilogue + store burst (4 coalesced float4).
        #pragma unroll
        for (int r = 0; r < G; ++r) {
            float cs = 0.f;
            #pragma unroll
            for (int w = 0; w < 7; ++w)
                if (w < wv) cs = fmaf(cs, d256, ws[grp][r][w]);
            const float C = fmaf(cs, dpow, es[r]);
            float4 o4;
            o4.x = fmaf(xv[r].x, gv.x, C                   + bv.x);
            o4.y = fmaf(xv[r].y, gv.y, fmaf(C, d,  lp1[r]) + bv.y);
            o4.z = fmaf(xv[r].z, gv.z, fmaf(C, d2, lp2[r]) + bv.z);
            o4.w = fmaf(xv[r].w, gv.w, fmaf(C, d3, lp3[r]) + bv.w);
            *(float4*)(out + base + (long)(grp * G + r) * SEQ + off) = o4;
        }

        if (grp + 1 < NGROUPS) {
            #pragma unroll
            for (int r = 0; r < G; ++r) xv[r] = xn[r];
        }
    }
}

extern "C" void kernel_launch(void* const* d_in, const int* in_sizes, int n_in,
                              void* d_out, int out_size, void* d_ws, size_t ws_size,
                              hipStream_t stream) {
    const float* x           = (const float*)d_in[0];
    const float* weight      = (const float*)d_in[1];
    const float* diag_weight = (const float*)d_in[2];
    const float* bias        = (const float*)d_in[3];
    const float* decay       = (const float*)d_in[4];
    float* out = (float*)d_out;

    const int rows = in_sizes[0] / SEQ;  // B*E = 16384
    decay_scan_kernel<<<rows / ROWS_PER_BLOCK, THREADS, 0, stream>>>(
        x, weight, diag_weight, bias, decay, out);
}